// Round 9
// baseline (627.026 us; speedup 1.0000x reference)
//
#include <hip/hip_runtime.h>
#include <hip/hip_bf16.h>

#define Bn 8
#define Nn 207
#define Tn 12
#define Cn 64
#define Ln (Nn*Tn)      // 2484
#define LP 2496         // padded to 64
#define NT 39           // LP/64
#define NB 104          // n-pair blocks per batch (24 rows each)

typedef unsigned int u32;
typedef unsigned short u16;
typedef _Float16 f16;
typedef __attribute__((ext_vector_type(4))) _Float16 half4;
typedef __attribute__((ext_vector_type(4))) float floatx4;

__device__ __forceinline__ u16 f2h(float f) { f16 h = (f16)f; return *(u16*)&h; }

// ---------------- ws layout ----------------
// u16 offsets:
#define U_WA   0            // f16 [k][cig][co][8]  12288
#define U_WB   12288        // 12288 -> 24576
#define U_WVT  24576        // f16 [o][c] 4096 -> 28672
// float offsets:
#define F_WK   14336        // fp32 [c][8] 512
#define F_WQ   14848        // fp32 [c][8] 512
// u16 offsets:
#define U_K    30720        // f16 [Bn][LP][8]        159744 -> 190464
#define U_Q    190464       // f16 [Bn][LP][8]        159744 -> 350208
#define U_HT   350208       // f16 [Bn][NT][64][64]  1277952 -> 1628160 (3.26 MB)

// ---------------- kernel 0: weight convert + pad zeroing ----------
__global__ __launch_bounds__(256) void prep_kernel(
    const float* __restrict__ wA, const float* __restrict__ wB,
    const float* __restrict__ wq, const float* __restrict__ wk,
    const float* __restrict__ wv, float* __restrict__ ws)
{
    u16* wsu = (u16*)ws;
    int idx = blockIdx.x * 256 + threadIdx.x;
    if (idx < 12288) {
        int j = idx & 7, co = (idx >> 3) & 63, cig = (idx >> 9) & 7, k = idx >> 12;
        wsu[U_WA + idx] = f2h(wA[(co*64 + cig*8 + j)*3 + k]);
    } else if (idx < 24576) {
        int i = idx - 12288;
        int j = i & 7, co = (i >> 3) & 63, cig = (i >> 9) & 7, k = i >> 12;
        wsu[U_WB + i] = f2h(wB[(co*64 + cig*8 + j)*3 + k]);
    } else if (idx < 28672) {
        int j = idx - 24576;
        wsu[U_WVT + j] = f2h(wv[j]);
    } else if (idx < 29184) {
        int j = idx - 28672; int o = j & 7, c = j >> 3;
        ws[F_WK + j] = wk[o*Cn + c];
    } else if (idx < 29696) {
        int j = idx - 29184; int o = j & 7, c = j >> 3;
        ws[F_WQ + j] = wq[o*Cn + c];
    } else if (idx < 31232) {
        int j = idx - 29696;            // zero k/q pad rows Ln..LP-1
        int b = j / 192, rem = j - b*192;
        int which = rem / 96, rr = rem - which*96;
        wsu[(which ? U_Q : U_K) + (size_t)b*LP*8 + Ln*8 + rr] = 0;
    } else if (idx < 37376) {
        int j = idx - 31232;            // zero hT tail: tile 38, m-local 52..63
        int b = j / 768, rem = j - b*768;
        int c = rem / 12, mm = 52 + (rem - c*12);
        wsu[U_HT + (size_t)b*NT*4096 + (size_t)(NT-1)*4096 + c*64 + mm] = 0;
    }
}

// ---------------- kernel 1: conv + GLU + k/q proj + hT transpose -----------
// one block per (b, n); software-pipelined weight prefetch
__global__ __launch_bounds__(256, 3) void conv_k_kernel(
    const float* __restrict__ X,
    const float* __restrict__ bA, const float* __restrict__ bB,
    const float* __restrict__ bk, const float* __restrict__ bq,
    float* __restrict__ ws, float* __restrict__ out)
{
    __shared__ float xs[Tn*Cn];
    __shared__ float hs[Tn*Cn];
    __shared__ float wkq_s[1024];      // wk[c][8] then wq[c][8]
    int b = blockIdx.x / Nn;
    int n = blockIdx.x % Nn;
    int tid = threadIdx.x;

    const float* Xp = X + (size_t)(b*Nn + n)*Tn*Cn;
    for (int i = tid; i < (Tn*Cn)/4; i += 256)
        ((float4*)xs)[i] = ((const float4*)Xp)[i];
    ((float4*)wkq_s)[tid] = ((const float4*)(ws + F_WK))[tid];
    __syncthreads();

    int co = tid & 63;
    int tg = tid >> 6;                 // rows t = 3tg .. 3tg+2
    float aA[3] = {bA[co], bA[co], bA[co]};
    float aB[3] = {bB[co], bB[co], bB[co]};

    const u16* wap = (const u16*)ws + U_WA;
    const u16* wbp = (const u16*)ws + U_WB;
    int tb = tg*3 - 2;

    uint4 wa[2][3], wb[2][3];
    #pragma unroll
    for (int k = 0; k < 3; ++k) {
        wa[0][k] = *(const uint4*)(wap + ((k*8 + 0)*64 + co)*8);
        wb[0][k] = *(const uint4*)(wbp + ((k*8 + 0)*64 + co)*8);
    }

    #pragma unroll
    for (int cig = 0; cig < 8; ++cig) {
        int cur = cig & 1;
        if (cig < 7) {
            int nxt = cur ^ 1;
            #pragma unroll
            for (int k = 0; k < 3; ++k) {
                wa[nxt][k] = *(const uint4*)(wap + ((k*8 + cig + 1)*64 + co)*8);
                wb[nxt][k] = *(const uint4*)(wbp + ((k*8 + cig + 1)*64 + co)*8);
            }
        }
        #pragma unroll
        for (int d = 0; d < 5; ++d) {
            int tp = tb + d;
            float xrow[8];
            if (tp >= 0) {
                float4 xa = *(const float4*)(xs + tp*Cn + cig*8);
                float4 xb = *(const float4*)(xs + tp*Cn + cig*8 + 4);
                xrow[0]=xa.x; xrow[1]=xa.y; xrow[2]=xa.z; xrow[3]=xa.w;
                xrow[4]=xb.x; xrow[5]=xb.y; xrow[6]=xb.z; xrow[7]=xb.w;
            } else {
                #pragma unroll
                for (int j = 0; j < 8; ++j) xrow[j] = 0.f;
            }
            #pragma unroll
            for (int k = 0; k < 3; ++k) {
                int tt = d - k;
                if (tt >= 0 && tt < 3) {
                    const f16* pa = (const f16*)&wa[cur][k];
                    const f16* pb = (const f16*)&wb[cur][k];
                    #pragma unroll
                    for (int j = 0; j < 8; ++j) {
                        aA[tt] += xrow[j] * (float)pa[j];
                        aB[tt] += xrow[j] * (float)pb[j];
                    }
                }
            }
        }
    }

    #pragma unroll
    for (int tt = 0; tt < 3; ++tt) {
        int t = tg*3 + tt;
        float hv = aA[tt] * (1.f / (1.f + __expf(-aB[tt])));
        hs[t*Cn + co] = hv;
        out[((size_t)b*Ln + (size_t)n*Tn + t)*Cn + co] = hv;   // fp32 h
    }
    __syncthreads();

    // k/q projections + hT transpose
    if (tid < 96) {
        int r = tid >> 3, o = tid & 7;
        float acc = bk[o];
        for (int c = 0; c < Cn; ++c) acc += hs[r*Cn + c] * wkq_s[c*8 + o];
        ((u16*)ws)[U_K + (size_t)b*LP*8 + ((size_t)n*Tn + r)*8 + o] = f2h(acc);
    } else if (tid < 192) {
        int r = (tid - 96) >> 3, o = tid & 7;
        float acc = bq[o];
        for (int c = 0; c < Cn; ++c) acc += hs[r*Cn + c] * wkq_s[512 + c*8 + o];
        ((u16*)ws)[U_Q + (size_t)b*LP*8 + ((size_t)n*Tn + r)*8 + o] = f2h(acc);
    }
    {
        int j = tid >> 6, c = tid & 63;
        if (j < 3) {
            int m = n*Tn + 4*j;        // 4-aligned, never crosses a 64-tile
            u32 p0 = ((u32)f2h(hs[(4*j+1)*Cn + c]) << 16) | f2h(hs[(4*j+0)*Cn + c]);
            u32 p1 = ((u32)f2h(hs[(4*j+3)*Cn + c]) << 16) | f2h(hs[(4*j+2)*Cn + c]);
            u16* ht = (u16*)ws + U_HT + (size_t)b*NT*4096 + (size_t)(m >> 6)*4096 + c*64 + (m & 63);
            *(uint2*)ht = make_uint2(p0, p1);
        }
    }
}

// ---------------- kernel 2: register-fused flash attention, pipelined ------
// one block per (b, n-pair): 24 rows. K=16 MFMAs; QK C-layout == PV B-layout.
// Double-buffered register prefetch of tile t+4 while computing tile t.
__global__ __launch_bounds__(256, 3) void attn_kernel(
    const float* __restrict__ gamma, const float* __restrict__ bv,
    const float* __restrict__ ws, float* __restrict__ out)
{
    __shared__ float part[4*64*24];    // [w][c][r] partial ha
    __shared__ float den_part[4][32];

    int b  = blockIdx.x / NB;
    int nb = blockIdx.x % NB;
    int R0 = nb*24;
    int tid = threadIdx.x;
    int lane = tid & 63;
    int w = tid >> 6;
    int rm = lane & 15;
    int quad = lane >> 4;

    const u16* wsu = (const u16*)ws;
    const u16* kb = wsu + U_K  + (size_t)b*LP*8;
    const u16* qb = wsu + U_Q  + (size_t)b*LP*8;
    const u16* hb = wsu + U_HT + (size_t)b*NT*4096;

    // q B-frags (d-pad quads 2,3 = 0)
    half4 qf[2];
    #pragma unroll
    for (int g = 0; g < 2; ++g) {
        uint2 u = make_uint2(0, 0);
        int row = R0 + g*16 + rm;
        if (row >= LP) row = LP - 1;
        if (quad < 2) u = *(const uint2*)(qb + (size_t)row*8 + 4*quad);
        qf[g] = *(half4*)&u;
    }

    floatx4 acc[4][2];
    #pragma unroll
    for (int cs = 0; cs < 4; ++cs)
        #pragma unroll
        for (int g = 0; g < 2; ++g) acc[cs][g] = (floatx4){0.f, 0.f, 0.f, 0.f};
    float dsum[2] = {0.f, 0.f};

    uint2 kbuf[2][4];
    uint2 hbuf[2][16];

#define LOADT(B_, T_) {                                                        \
    int tc = ((T_) < NT) ? (T_) : (NT-1);                                      \
    const u16* kt = kb + (size_t)tc*512;                                       \
    const u16* ht = hb + (size_t)tc*4096;                                      \
    _Pragma("unroll")                                                          \
    for (int ss = 0; ss < 4; ++ss) {                                           \
        kbuf[B_][ss] = (quad < 2) ? *(const uint2*)(kt + (ss*16 + rm)*8 + 4*quad) \
                                  : make_uint2(0, 0);                          \
        _Pragma("unroll")                                                      \
        for (int cs = 0; cs < 4; ++cs)                                         \
            hbuf[B_][ss*4 + cs] = *(const uint2*)(ht + (cs*16 + rm)*64 + ss*16 + 4*quad); \
    } }

#define COMPT(B_, T_) {                                                        \
    bool tail = ((T_)*64 + 64 > Ln);                                           \
    _Pragma("unroll")                                                          \
    for (int ss = 0; ss < 4; ++ss) {                                           \
        half4 kf = *(half4*)&kbuf[B_][ss];                                     \
        floatx4 s0 = {0.f,0.f,0.f,0.f}, s1 = {0.f,0.f,0.f,0.f};                \
        s0 = __builtin_amdgcn_mfma_f32_16x16x16f16(kf, qf[0], s0, 0, 0, 0);    \
        s1 = __builtin_amdgcn_mfma_f32_16x16x16f16(kf, qf[1], s1, 0, 0, 0);    \
        half4 e0, e1;                                                          \
        int mb = (T_)*64 + ss*16 + 4*quad;                                     \
        _Pragma("unroll")                                                      \
        for (int i = 0; i < 4; ++i) {                                          \
            float ev0 = __expf(s0[i]);                                         \
            float ev1 = __expf(s1[i]);                                         \
            if (tail && (mb + i >= Ln)) { ev0 = 0.f; ev1 = 0.f; }              \
            dsum[0] += ev0; dsum[1] += ev1;                                    \
            e0[i] = (f16)ev0; e1[i] = (f16)ev1;                                \
        }                                                                      \
        _Pragma("unroll")                                                      \
        for (int cs = 0; cs < 4; ++cs) {                                       \
            half4 af = *(half4*)&hbuf[B_][ss*4 + cs];                          \
            acc[cs][0] = __builtin_amdgcn_mfma_f32_16x16x16f16(af, e0, acc[cs][0], 0, 0, 0); \
            acc[cs][1] = __builtin_amdgcn_mfma_f32_16x16x16f16(af, e1, acc[cs][1], 0, 0, 0); \
        }                                                                      \
    } }

    LOADT(0, w)
    #pragma unroll
    for (int i = 0; i < 10; ++i) {
        int t = w + 4*i;
        int cur = i & 1;
        if (i < 9) { int tn = t + 4; LOADT(cur ^ 1, tn) }
        COMPT(cur, t)
    }
#undef LOADT
#undef COMPT

    // denominator partials
    #pragma unroll
    for (int g = 0; g < 2; ++g) {
        float s_ = dsum[g];
        s_ += __shfl_xor(s_, 16, 64);
        s_ += __shfl_xor(s_, 32, 64);
        if (quad == 0) den_part[w][g*16 + rm] = s_;
    }

    // partial ha: D[c_local=4*quad+reg][r=rm]
    float* pw = part + w*1536;
    #pragma unroll
    for (int cs = 0; cs < 4; ++cs)
        #pragma unroll
        for (int g = 0; g < 2; ++g) {
            if (g == 0 || rm < 8) {
                int r = g*16 + rm;
                #pragma unroll
                for (int i = 0; i < 4; ++i)
                    pw[(cs*16 + quad*4 + i)*24 + r] = acc[cs][g][i];
            }
        }
    __syncthreads();

    for (int j = tid; j < 1536; j += 256)
        part[j] = part[j] + part[1536 + j] + part[3072 + j] + part[4608 + j];
    __syncthreads();

    // epilogue: Wv (f16 rows) + gamma residual
    int o = tid & 63, rq = tid >> 6;
    float gam = gamma[0];
    float bvo = bv[o];
    const u16* wvr = wsu + U_WVT + o*64;
    uint4 wvu[8];
    #pragma unroll
    for (int x = 0; x < 8; ++x) wvu[x] = *(const uint4*)(wvr + x*8);
    #pragma unroll
    for (int rr = 0; rr < 6; ++rr) {
        int r = rq*6 + rr;
        int row = R0 + r;
        if (row < Ln) {
            float den = den_part[0][r] + den_part[1][r] + den_part[2][r] + den_part[3][r];
            float p = 0.f;
            #pragma unroll
            for (int x = 0; x < 8; ++x) {
                const f16* hh = (const f16*)&wvu[x];
                #pragma unroll
                for (int i = 0; i < 8; ++i)
                    p += (float)hh[i] * part[(x*8 + i)*24 + r];
            }
            size_t gi = ((size_t)b*Ln + row)*64 + o;
            out[gi] = gam*(bvo + p/den) + out[gi];
        }
    }
}

// ---------------- launch ----------------
extern "C" void kernel_launch(void* const* d_in, const int* in_sizes, int n_in,
                              void* d_out, int out_size, void* d_ws, size_t ws_size,
                              hipStream_t stream) {
    const float* X     = (const float*)d_in[0];
    const float* wA    = (const float*)d_in[1];
    const float* bA    = (const float*)d_in[2];
    const float* wB    = (const float*)d_in[3];
    const float* bB    = (const float*)d_in[4];
    const float* wq    = (const float*)d_in[5];
    const float* bq    = (const float*)d_in[6];
    const float* wk    = (const float*)d_in[7];
    const float* bk    = (const float*)d_in[8];
    const float* wv    = (const float*)d_in[9];
    const float* bv    = (const float*)d_in[10];
    const float* gamma = (const float*)d_in[11];
    float* out = (float*)d_out;
    float* ws  = (float*)d_ws;

    prep_kernel<<<146, 256, 0, stream>>>(wA, wB, wq, wk, wv, ws);
    conv_k_kernel<<<Bn*Nn, 256, 0, stream>>>(X, bA, bB, bk, bq, ws, out);
    attn_kernel<<<Bn*NB, 256, 0, stream>>>(gamma, bv, ws, out);
}

// Round 10
// 286.653 us; speedup vs baseline: 2.1874x; 2.1874x over previous
//
#include <hip/hip_runtime.h>
#include <hip/hip_bf16.h>

#define Bn 8
#define Nn 207
#define Tn 12
#define Cn 64
#define Ln (Nn*Tn)      // 2484
#define LP 2496         // padded to 64
#define NT 39           // LP/64
#define NB 104          // n-pair blocks per batch (24 rows each)

typedef unsigned int u32;
typedef unsigned short u16;
typedef _Float16 f16;
typedef __attribute__((ext_vector_type(4))) _Float16 half4;
typedef __attribute__((ext_vector_type(4))) float floatx4;

__device__ __forceinline__ u16 f2h(float f) { f16 h = (f16)f; return *(u16*)&h; }
__device__ __forceinline__ float h2f_lo(u32 u) { u16 x = (u16)u;        f16 h = *(f16*)&x; return (float)h; }
__device__ __forceinline__ float h2f_hi(u32 u) { u16 x = (u16)(u >> 16); f16 h = *(f16*)&x; return (float)h; }

// ---------------- ws layout ----------------
#define W_PW   0            // u32 [k][cig][j][co] packed {wA,wB} : 12288 u32 (byte 0..49152)
#define U_WVT  24576        // f16 [o][c] 4096 u16 (byte 49152..57344)
#define F_WK   14336        // fp32 [c][8] 512 (byte 57344..59392)
#define F_WQ   14848        // fp32 [c][8] 512 (byte 59392..61440)
#define U_K    30720        // f16 [Bn][LP][8]   159744 u16
#define U_Q    190464       // f16 [Bn][LP][8]   159744 u16
// hT swizzled to PV A-frag order: [b][tile][ss][cs][rm*4+quad][i]
#define U_HT   350208       // f16 [Bn][NT][16][256] 1277952 u16 -> ends byte 3,256,320

// element (c, m): tile=m>>6, mloc=m&63, ss=mloc>>4, q=(mloc>>2)&3, i=m&3, cs=c>>4, rm=c&15
// u16 addr = U_HT + b*NT*4096 + (tile*16 + ss*4 + cs)*256 + (rm*4+q)*4 + i

// ---------------- kernel 0: weight pack + pad zeroing ----------
__global__ __launch_bounds__(256) void prep_kernel(
    const float* __restrict__ wA, const float* __restrict__ wB,
    const float* __restrict__ wq, const float* __restrict__ wk,
    const float* __restrict__ wv, float* __restrict__ ws)
{
    u16* wsu = (u16*)ws;
    u32* wsw = (u32*)ws;
    int idx = blockIdx.x * 256 + threadIdx.x;
    if (idx < 12288) {
        int co = idx & 63, j = (idx >> 6) & 7, cig = (idx >> 9) & 7, k = idx >> 12;
        int src = (co*64 + cig*8 + j)*3 + k;
        wsw[W_PW + idx] = (u32)f2h(wA[src]) | ((u32)f2h(wB[src]) << 16);
    } else if (idx < 16384) {
        int j = idx - 12288;
        wsu[U_WVT + j] = f2h(wv[j]);
    } else if (idx < 16896) {
        int j = idx - 16384; int o = j & 7, c = j >> 3;
        ws[F_WK + j] = wk[o*Cn + c];
    } else if (idx < 17408) {
        int j = idx - 16896; int o = j & 7, c = j >> 3;
        ws[F_WQ + j] = wq[o*Cn + c];
    } else if (idx < 18944) {
        int j = idx - 17408;            // zero k/q pad rows Ln..LP-1
        int b = j / 192, rem = j - b*192;
        int which = rem / 96, rr = rem - which*96;
        wsu[(which ? U_Q : U_K) + (size_t)b*LP*8 + Ln*8 + rr] = 0;
    } else if (idx < 25088) {
        int j = idx - 18944;            // zero hT tail: tile 38, mloc 52..63 (swizzled)
        int b = j / 768, rem = j - b*768;
        int c = rem / 12, mm = 52 + (rem - c*12);
        int ss = mm >> 4, q = (mm >> 2) & 3, i = mm & 3;
        int cs = c >> 4, rm = c & 15;
        wsu[U_HT + (size_t)b*NT*4096 + ((38*16 + ss*4 + cs)*256 + (rm*4 + q)*4 + i)] = 0;
    }
}

// ---------------- kernel 1: conv + GLU + k/q proj + swizzled hT ------------
// one block per (b, n); weights staged in LDS (conflict-free reads)
__global__ __launch_bounds__(256, 2) void conv_k_kernel(
    const float* __restrict__ X,
    const float* __restrict__ bA, const float* __restrict__ bB,
    const float* __restrict__ bk, const float* __restrict__ bq,
    float* __restrict__ ws, float* __restrict__ out)
{
    __shared__ u32   w_s[12288];       // 48 KB packed weights
    __shared__ float xs[Tn*Cn];
    __shared__ float hs[Tn*Cn];
    __shared__ float wkq_s[1024];
    int b = blockIdx.x / Nn;
    int n = blockIdx.x % Nn;
    int tid = threadIdx.x;

    // stage weights (coalesced uint4), x, wk/wq
    for (int i = tid; i < 3072; i += 256)
        ((uint4*)w_s)[i] = ((const uint4*)ws)[i];
    const float* Xp = X + (size_t)(b*Nn + n)*Tn*Cn;
    for (int i = tid; i < (Tn*Cn)/4; i += 256)
        ((float4*)xs)[i] = ((const float4*)Xp)[i];
    ((float4*)wkq_s)[tid] = ((const float4*)(ws + F_WK))[tid];
    __syncthreads();

    int co = tid & 63;
    int tg = tid >> 6;                 // rows t = 3tg..3tg+2
    float aA[3] = {bA[co], bA[co], bA[co]};
    float aB[3] = {bB[co], bB[co], bB[co]};
    int tb = tg*3 - 2;

    #pragma unroll
    for (int cig = 0; cig < 8; ++cig) {
        float xr[5][8];
        #pragma unroll
        for (int d = 0; d < 5; ++d) {
            int tp = tb + d;
            if (tp >= 0) {
                float4 xa = *(const float4*)(xs + tp*Cn + cig*8);
                float4 xb = *(const float4*)(xs + tp*Cn + cig*8 + 4);
                xr[d][0]=xa.x; xr[d][1]=xa.y; xr[d][2]=xa.z; xr[d][3]=xa.w;
                xr[d][4]=xb.x; xr[d][5]=xb.y; xr[d][6]=xb.z; xr[d][7]=xb.w;
            } else {
                #pragma unroll
                for (int j = 0; j < 8; ++j) xr[d][j] = 0.f;
            }
        }
        #pragma unroll
        for (int k = 0; k < 3; ++k) {
            #pragma unroll
            for (int j = 0; j < 8; ++j) {
                u32 p = w_s[((k*8 + cig)*8 + j)*64 + co];
                float wa = h2f_lo(p), wb = h2f_hi(p);
                #pragma unroll
                for (int tt = 0; tt < 3; ++tt) {
                    aA[tt] += xr[tt + k][j] * wa;
                    aB[tt] += xr[tt + k][j] * wb;
                }
            }
        }
    }

    #pragma unroll
    for (int tt = 0; tt < 3; ++tt) {
        int t = tg*3 + tt;
        float hv = aA[tt] * (1.f / (1.f + __expf(-aB[tt])));
        hs[t*Cn + co] = hv;
        out[((size_t)b*Ln + (size_t)n*Tn + t)*Cn + co] = hv;   // fp32 h
    }
    __syncthreads();

    // k/q projections
    if (tid < 96) {
        int r = tid >> 3, o = tid & 7;
        float acc = bk[o];
        for (int c = 0; c < Cn; ++c) acc += hs[r*Cn + c] * wkq_s[c*8 + o];
        ((u16*)ws)[U_K + (size_t)b*LP*8 + ((size_t)n*Tn + r)*8 + o] = f2h(acc);
    } else if (tid < 192) {
        int r = (tid - 96) >> 3, o = tid & 7;
        float acc = bq[o];
        for (int c = 0; c < Cn; ++c) acc += hs[r*Cn + c] * wkq_s[512 + c*8 + o];
        ((u16*)ws)[U_Q + (size_t)b*LP*8 + ((size_t)n*Tn + r)*8 + o] = f2h(acc);
    }
    // swizzled hT write: 4 consecutive m (4-aligned) = one uint2 at a single (ss,q)
    {
        int jj = tid >> 6, c = tid & 63;
        if (jj < 3) {
            int m = n*Tn + 4*jj;
            int tile = m >> 6, mloc = m & 63;
            int ss = mloc >> 4, q = (mloc >> 2) & 3;
            int cs = c >> 4, rm = c & 15;
            u32 p0 = ((u32)f2h(hs[(4*jj+1)*Cn + c]) << 16) | f2h(hs[(4*jj+0)*Cn + c]);
            u32 p1 = ((u32)f2h(hs[(4*jj+3)*Cn + c]) << 16) | f2h(hs[(4*jj+2)*Cn + c]);
            u16* ht = (u16*)ws + U_HT + (size_t)b*NT*4096
                    + ((tile*16 + ss*4 + cs)*256 + (rm*4 + q)*4);
            *(uint2*)ht = make_uint2(p0, p1);
        }
    }
}

// ---------------- kernel 2: register-fused flash attention -----------------
// K=16 MFMAs; QK C-layout == PV B-layout (e in registers, no barriers).
// 1-tile-ahead prefetch into NAMED registers (literal buffer ids; spill-proof).
__global__ __launch_bounds__(256, 3) void attn_kernel(
    const float* __restrict__ gamma, const float* __restrict__ bv,
    const float* __restrict__ ws, float* __restrict__ out)
{
    __shared__ float part[4*64*24];    // [w][c][r] partial ha
    __shared__ float den_part[4][32];

    int b  = blockIdx.x / NB;
    int nb = blockIdx.x % NB;
    int R0 = nb*24;
    int tid = threadIdx.x;
    int lane = tid & 63;
    int w = tid >> 6;
    int rm = lane & 15;
    int quad = lane >> 4;

    const u16* wsu = (const u16*)ws;
    const u16* kb = wsu + U_K  + (size_t)b*LP*8;
    const u16* qb = wsu + U_Q  + (size_t)b*LP*8;
    const u16* hb = wsu + U_HT + (size_t)b*NT*4096;

    // q B-frags (d-pad quads 2,3 = 0)
    half4 qf0, qf1;
    {
        uint2 u0 = make_uint2(0, 0), u1 = make_uint2(0, 0);
        int r0 = R0 + rm;       if (r0 >= LP) r0 = LP - 1;
        int r1 = R0 + 16 + rm;  if (r1 >= LP) r1 = LP - 1;
        if (quad < 2) {
            u0 = *(const uint2*)(qb + (size_t)r0*8 + 4*quad);
            u1 = *(const uint2*)(qb + (size_t)r1*8 + 4*quad);
        }
        qf0 = *(half4*)&u0; qf1 = *(half4*)&u1;
    }

    floatx4 acc[4][2];
    #pragma unroll
    for (int cs = 0; cs < 4; ++cs)
        #pragma unroll
        for (int g = 0; g < 2; ++g) acc[cs][g] = (floatx4){0.f, 0.f, 0.f, 0.f};
    float dsum0 = 0.f, dsum1 = 0.f;

    uint2 k0_0,k0_1,k0_2,k0_3, k1_0,k1_1,k1_2,k1_3;
    uint2 h0_0,h0_1,h0_2,h0_3,h0_4,h0_5,h0_6,h0_7,h0_8,h0_9,h0_10,h0_11,h0_12,h0_13,h0_14,h0_15;
    uint2 h1_0,h1_1,h1_2,h1_3,h1_4,h1_5,h1_6,h1_7,h1_8,h1_9,h1_10,h1_11,h1_12,h1_13,h1_14,h1_15;

#define LDK(kt, SS) ((quad < 2) ? *(const uint2*)((kt) + ((SS)*16 + rm)*8 + 4*quad) : make_uint2(0,0))
#define LDH(ht, IDX) (*(const uint2*)((ht) + (IDX)*256 + lane*4))

#define LOADT(B, T) {                                                          \
    int tc = ((T) < NT) ? (T) : (NT-1);                                        \
    const u16* kt_ = kb + (size_t)tc*512;                                      \
    const u16* ht_ = hb + (size_t)tc*4096;                                     \
    k##B##_0 = LDK(kt_, 0); k##B##_1 = LDK(kt_, 1);                            \
    k##B##_2 = LDK(kt_, 2); k##B##_3 = LDK(kt_, 3);                            \
    h##B##_0  = LDH(ht_, 0);  h##B##_1  = LDH(ht_, 1);                         \
    h##B##_2  = LDH(ht_, 2);  h##B##_3  = LDH(ht_, 3);                         \
    h##B##_4  = LDH(ht_, 4);  h##B##_5  = LDH(ht_, 5);                         \
    h##B##_6  = LDH(ht_, 6);  h##B##_7  = LDH(ht_, 7);                         \
    h##B##_8  = LDH(ht_, 8);  h##B##_9  = LDH(ht_, 9);                         \
    h##B##_10 = LDH(ht_, 10); h##B##_11 = LDH(ht_, 11);                        \
    h##B##_12 = LDH(ht_, 12); h##B##_13 = LDH(ht_, 13);                        \
    h##B##_14 = LDH(ht_, 14); h##B##_15 = LDH(ht_, 15);                        \
}

#define COMPSS(KR, HA, HB_, HC, HD, T, SS) {                                   \
    half4 kf = *(half4*)&KR;                                                   \
    floatx4 s0 = {0.f,0.f,0.f,0.f}, s1 = {0.f,0.f,0.f,0.f};                    \
    s0 = __builtin_amdgcn_mfma_f32_16x16x16f16(kf, qf0, s0, 0, 0, 0);          \
    s1 = __builtin_amdgcn_mfma_f32_16x16x16f16(kf, qf1, s1, 0, 0, 0);          \
    half4 e0, e1;                                                              \
    int mb = (T)*64 + (SS)*16 + 4*quad;                                        \
    _Pragma("unroll")                                                          \
    for (int i_ = 0; i_ < 4; ++i_) {                                           \
        float ev0 = (mb + i_ < Ln) ? __expf(s0[i_]) : 0.f;                     \
        float ev1 = (mb + i_ < Ln) ? __expf(s1[i_]) : 0.f;                     \
        dsum0 += ev0; dsum1 += ev1;                                            \
        e0[i_] = (f16)ev0; e1[i_] = (f16)ev1;                                  \
    }                                                                          \
    half4 a0_ = *(half4*)&HA, a1_ = *(half4*)&HB_, a2_ = *(half4*)&HC, a3_ = *(half4*)&HD; \
    acc[0][0] = __builtin_amdgcn_mfma_f32_16x16x16f16(a0_, e0, acc[0][0], 0, 0, 0); \
    acc[0][1] = __builtin_amdgcn_mfma_f32_16x16x16f16(a0_, e1, acc[0][1], 0, 0, 0); \
    acc[1][0] = __builtin_amdgcn_mfma_f32_16x16x16f16(a1_, e0, acc[1][0], 0, 0, 0); \
    acc[1][1] = __builtin_amdgcn_mfma_f32_16x16x16f16(a1_, e1, acc[1][1], 0, 0, 0); \
    acc[2][0] = __builtin_amdgcn_mfma_f32_16x16x16f16(a2_, e0, acc[2][0], 0, 0, 0); \
    acc[2][1] = __builtin_amdgcn_mfma_f32_16x16x16f16(a2_, e1, acc[2][1], 0, 0, 0); \
    acc[3][0] = __builtin_amdgcn_mfma_f32_16x16x16f16(a3_, e0, acc[3][0], 0, 0, 0); \
    acc[3][1] = __builtin_amdgcn_mfma_f32_16x16x16f16(a3_, e1, acc[3][1], 0, 0, 0); \
}

#define COMPT(B, T) {                                                          \
    COMPSS(k##B##_0, h##B##_0,  h##B##_1,  h##B##_2,  h##B##_3,  T, 0)         \
    COMPSS(k##B##_1, h##B##_4,  h##B##_5,  h##B##_6,  h##B##_7,  T, 1)         \
    COMPSS(k##B##_2, h##B##_8,  h##B##_9,  h##B##_10, h##B##_11, T, 2)         \
    COMPSS(k##B##_3, h##B##_12, h##B##_13, h##B##_14, h##B##_15, T, 3)         \
}

    LOADT(0, w)
    for (int i = 0; i < 5; ++i) {
        int t0 = w + 8*i;
        LOADT(1, t0 + 4)
        COMPT(0, t0)
        LOADT(0, t0 + 8)
        COMPT(1, t0 + 4)
    }
#undef LOADT
#undef COMPT
#undef COMPSS
#undef LDK
#undef LDH

    // denominator partials
    {
        float s_ = dsum0;
        s_ += __shfl_xor(s_, 16, 64);
        s_ += __shfl_xor(s_, 32, 64);
        if (quad == 0) den_part[w][rm] = s_;
        float t_ = dsum1;
        t_ += __shfl_xor(t_, 16, 64);
        t_ += __shfl_xor(t_, 32, 64);
        if (quad == 0) den_part[w][16 + rm] = t_;
    }

    // partial ha: D[c_local=4*quad+reg][r=rm]
    float* pw = part + w*1536;
    #pragma unroll
    for (int cs = 0; cs < 4; ++cs) {
        #pragma unroll
        for (int i = 0; i < 4; ++i)
            pw[(cs*16 + quad*4 + i)*24 + rm] = acc[cs][0][i];
        if (rm < 8) {
            #pragma unroll
            for (int i = 0; i < 4; ++i)
                pw[(cs*16 + quad*4 + i)*24 + 16 + rm] = acc[cs][1][i];
        }
    }
    __syncthreads();

    for (int j = tid; j < 1536; j += 256)
        part[j] = part[j] + part[1536 + j] + part[3072 + j] + part[4608 + j];
    __syncthreads();

    // epilogue: Wv (f16 rows) + gamma residual
    int o = tid & 63, rq = tid >> 6;
    float gam = gamma[0];
    float bvo = bv[o];
    const u16* wvr = wsu + U_WVT + o*64;
    uint4 wvu[8];
    #pragma unroll
    for (int x = 0; x < 8; ++x) wvu[x] = *(const uint4*)(wvr + x*8);
    #pragma unroll
    for (int rr = 0; rr < 6; ++rr) {
        int r = rq*6 + rr;
        int row = R0 + r;
        if (row < Ln) {
            float den = den_part[0][r] + den_part[1][r] + den_part[2][r] + den_part[3][r];
            float p = 0.f;
            #pragma unroll
            for (int x = 0; x < 8; ++x) {
                const f16* hh = (const f16*)&wvu[x];
                #pragma unroll
                for (int i = 0; i < 8; ++i)
                    p += (float)hh[i] * part[(x*8 + i)*24 + r];
            }
            size_t gi = ((size_t)b*Ln + row)*64 + o;
            out[gi] = gam*(bvo + p/den) + out[gi];
        }
    }
}

// ---------------- launch ----------------
extern "C" void kernel_launch(void* const* d_in, const int* in_sizes, int n_in,
                              void* d_out, int out_size, void* d_ws, size_t ws_size,
                              hipStream_t stream) {
    const float* X     = (const float*)d_in[0];
    const float* wA    = (const float*)d_in[1];
    const float* bA    = (const float*)d_in[2];
    const float* wB    = (const float*)d_in[3];
    const float* bB    = (const float*)d_in[4];
    const float* wq    = (const float*)d_in[5];
    const float* bq    = (const float*)d_in[6];
    const float* wk    = (const float*)d_in[7];
    const float* bk    = (const float*)d_in[8];
    const float* wv    = (const float*)d_in[9];
    const float* bv    = (const float*)d_in[10];
    const float* gamma = (const float*)d_in[11];
    float* out = (float*)d_out;
    float* ws  = (float*)d_ws;

    prep_kernel<<<98, 256, 0, stream>>>(wA, wB, wq, wk, wv, ws);
    conv_k_kernel<<<Bn*Nn, 256, 0, stream>>>(X, bA, bB, bk, bq, ws, out);
    attn_kernel<<<Bn*NB, 256, 0, stream>>>(gamma, bv, ws, out);
}

// Round 11
// 158.630 us; speedup vs baseline: 3.9527x; 1.8071x over previous
//
#include <hip/hip_runtime.h>
#include <hip/hip_bf16.h>

#define Bn 8
#define Nn 207
#define Tn 12
#define Cn 64
#define Ln (Nn*Tn)      // 2484
#define LP 2496         // padded to 64
#define NT 39           // LP/64
#define NB 104          // n-pair blocks per batch (24 rows each)

typedef unsigned int u32;
typedef unsigned short u16;
typedef _Float16 f16;
typedef __attribute__((ext_vector_type(4))) _Float16 half4;
typedef __attribute__((ext_vector_type(4))) float floatx4;

__device__ __forceinline__ u16 f2h(float f) { f16 h = (f16)f; return *(u16*)&h; }
__device__ __forceinline__ float h2f_lo(u32 u) { u16 x = (u16)u;        f16 h = *(f16*)&x; return (float)h; }
__device__ __forceinline__ float h2f_hi(u32 u) { u16 x = (u16)(u >> 16); f16 h = *(f16*)&x; return (float)h; }

// ---------------- ws layout ----------------
#define W_PW   0            // u32 [k][cig][j][co] packed {wA,wB} : 12288 u32
#define U_WVT  24576        // f16 [o][c] 4096 u16
#define F_WK   14336        // fp32 [c][8] 512 (float offsets)
#define F_WQ   14848        // fp32 [c][8] 512
#define U_K    30720        // f16 [Bn][LP][8]   159744 u16
#define U_Q    190464       // f16 [Bn][LP][8]   159744 u16
// hT swizzled to PV A-frag order: [b][tile][ss][cs][rm*4+quad][i]
#define U_HT   350208       // f16 [Bn][NT][16][256] 1277952 u16 -> ends byte 3,256,320

// ---------------- kernel 0: weight pack + pad zeroing ----------
__global__ __launch_bounds__(256) void prep_kernel(
    const float* __restrict__ wA, const float* __restrict__ wB,
    const float* __restrict__ wq, const float* __restrict__ wk,
    const float* __restrict__ wv, float* __restrict__ ws)
{
    u16* wsu = (u16*)ws;
    u32* wsw = (u32*)ws;
    int idx = blockIdx.x * 256 + threadIdx.x;
    if (idx < 12288) {
        int co = idx & 63, j = (idx >> 6) & 7, cig = (idx >> 9) & 7, k = idx >> 12;
        int src = (co*64 + cig*8 + j)*3 + k;
        wsw[W_PW + idx] = (u32)f2h(wA[src]) | ((u32)f2h(wB[src]) << 16);
    } else if (idx < 16384) {
        int j = idx - 12288;
        wsu[U_WVT + j] = f2h(wv[j]);
    } else if (idx < 16896) {
        int j = idx - 16384; int o = j & 7, c = j >> 3;
        ws[F_WK + j] = wk[o*Cn + c];
    } else if (idx < 17408) {
        int j = idx - 16896; int o = j & 7, c = j >> 3;
        ws[F_WQ + j] = wq[o*Cn + c];
    } else if (idx < 18944) {
        int j = idx - 17408;            // zero k/q pad rows Ln..LP-1
        int b = j / 192, rem = j - b*192;
        int which = rem / 96, rr = rem - which*96;
        wsu[(which ? U_Q : U_K) + (size_t)b*LP*8 + Ln*8 + rr] = 0;
    } else if (idx < 25088) {
        int j = idx - 18944;            // zero hT tail: tile 38, mloc 52..63 (swizzled)
        int b = j / 768, rem = j - b*768;
        int c = rem / 12, mm = 52 + (rem - c*12);
        int ss = mm >> 4, q = (mm >> 2) & 3, i = mm & 3;
        int cs = c >> 4, rm = c & 15;
        wsu[U_HT + (size_t)b*NT*4096 + ((38*16 + ss*4 + cs)*256 + (rm*4 + q)*4 + i)] = 0;
    }
}

// ---------------- kernel 1: conv + GLU + k/q proj + swizzled hT ------------
// one block per (b, n), XCD-affine: b = blockIdx & 7
__global__ __launch_bounds__(256, 2) void conv_k_kernel(
    const float* __restrict__ X,
    const float* __restrict__ bA, const float* __restrict__ bB,
    const float* __restrict__ bk, const float* __restrict__ bq,
    float* __restrict__ ws, float* __restrict__ out)
{
    __shared__ u32   w_s[12288];       // 48 KB packed weights
    __shared__ float xs[Tn*Cn];
    __shared__ float hs[Tn*Cn];
    __shared__ float wkq_s[1024];
    int b = blockIdx.x & 7;            // XCD-affinity swizzle (8 XCDs)
    int n = blockIdx.x >> 3;
    int tid = threadIdx.x;

    for (int i = tid; i < 3072; i += 256)
        ((uint4*)w_s)[i] = ((const uint4*)ws)[i];
    const float* Xp = X + (size_t)(b*Nn + n)*Tn*Cn;
    for (int i = tid; i < (Tn*Cn)/4; i += 256)
        ((float4*)xs)[i] = ((const float4*)Xp)[i];
    ((float4*)wkq_s)[tid] = ((const float4*)(ws + F_WK))[tid];
    __syncthreads();

    int co = tid & 63;
    int tg = tid >> 6;                 // rows t = 3tg..3tg+2
    float aA[3] = {bA[co], bA[co], bA[co]};
    float aB[3] = {bB[co], bB[co], bB[co]};
    int tb = tg*3 - 2;

    #pragma unroll 1                   // DO NOT unroll: full unroll spills xr -> scratch (R10: 392 MB WRITE)
    for (int cig = 0; cig < 8; ++cig) {
        float xr[5][8];
        #pragma unroll
        for (int d = 0; d < 5; ++d) {
            int tp = tb + d;
            if (tp >= 0) {
                float4 xa = *(const float4*)(xs + tp*Cn + cig*8);
                float4 xb = *(const float4*)(xs + tp*Cn + cig*8 + 4);
                xr[d][0]=xa.x; xr[d][1]=xa.y; xr[d][2]=xa.z; xr[d][3]=xa.w;
                xr[d][4]=xb.x; xr[d][5]=xb.y; xr[d][6]=xb.z; xr[d][7]=xb.w;
            } else {
                #pragma unroll
                for (int j = 0; j < 8; ++j) xr[d][j] = 0.f;
            }
        }
        #pragma unroll
        for (int k = 0; k < 3; ++k) {
            #pragma unroll
            for (int j = 0; j < 8; ++j) {
                u32 p = w_s[((k*8 + cig)*8 + j)*64 + co];
                float wa = h2f_lo(p), wb = h2f_hi(p);
                #pragma unroll
                for (int tt = 0; tt < 3; ++tt) {
                    aA[tt] += xr[tt + k][j] * wa;
                    aB[tt] += xr[tt + k][j] * wb;
                }
            }
        }
    }

    #pragma unroll
    for (int tt = 0; tt < 3; ++tt) {
        int t = tg*3 + tt;
        float hv = aA[tt] * (1.f / (1.f + __expf(-aB[tt])));
        hs[t*Cn + co] = hv;
        out[((size_t)b*Ln + (size_t)n*Tn + t)*Cn + co] = hv;   // fp32 h
    }
    __syncthreads();

    if (tid < 96) {
        int r = tid >> 3, o = tid & 7;
        float acc = bk[o];
        for (int c = 0; c < Cn; ++c) acc += hs[r*Cn + c] * wkq_s[c*8 + o];
        ((u16*)ws)[U_K + (size_t)b*LP*8 + ((size_t)n*Tn + r)*8 + o] = f2h(acc);
    } else if (tid < 192) {
        int r = (tid - 96) >> 3, o = tid & 7;
        float acc = bq[o];
        for (int c = 0; c < Cn; ++c) acc += hs[r*Cn + c] * wkq_s[512 + c*8 + o];
        ((u16*)ws)[U_Q + (size_t)b*LP*8 + ((size_t)n*Tn + r)*8 + o] = f2h(acc);
    }
    {
        int jj = tid >> 6, c = tid & 63;
        if (jj < 3) {
            int m = n*Tn + 4*jj;
            int tile = m >> 6, mloc = m & 63;
            int ss = mloc >> 4, q = (mloc >> 2) & 3;
            int cs = c >> 4, rm = c & 15;
            u32 p0 = ((u32)f2h(hs[(4*jj+1)*Cn + c]) << 16) | f2h(hs[(4*jj+0)*Cn + c]);
            u32 p1 = ((u32)f2h(hs[(4*jj+3)*Cn + c]) << 16) | f2h(hs[(4*jj+2)*Cn + c]);
            u16* ht = (u16*)ws + U_HT + (size_t)b*NT*4096
                    + ((tile*16 + ss*4 + cs)*256 + (rm*4 + q)*4);
            *(uint2*)ht = make_uint2(p0, p1);
        }
    }
}

// ---------------- kernel 2: register-fused flash attention -----------------
// XCD-affine: b = blockIdx & 7 -> one batch's hT/k/q/h stays in its XCD L2.
__global__ __launch_bounds__(256, 3) void attn_kernel(
    const float* __restrict__ gamma, const float* __restrict__ bv,
    const float* __restrict__ ws, float* __restrict__ out)
{
    __shared__ float part[4*64*24];    // [w][c][r] partial ha
    __shared__ float den_part[4][32];

    int b  = blockIdx.x & 7;           // XCD-affinity swizzle
    int nb = blockIdx.x >> 3;
    int R0 = nb*24;
    int tid = threadIdx.x;
    int lane = tid & 63;
    int w = tid >> 6;
    int rm = lane & 15;
    int quad = lane >> 4;

    const u16* wsu = (const u16*)ws;
    const u16* kb = wsu + U_K  + (size_t)b*LP*8;
    const u16* qb = wsu + U_Q  + (size_t)b*LP*8;
    const u16* hb = wsu + U_HT + (size_t)b*NT*4096;

    half4 qf0, qf1;
    {
        uint2 u0 = make_uint2(0, 0), u1 = make_uint2(0, 0);
        int r0 = R0 + rm;       if (r0 >= LP) r0 = LP - 1;
        int r1 = R0 + 16 + rm;  if (r1 >= LP) r1 = LP - 1;
        if (quad < 2) {
            u0 = *(const uint2*)(qb + (size_t)r0*8 + 4*quad);
            u1 = *(const uint2*)(qb + (size_t)r1*8 + 4*quad);
        }
        qf0 = *(half4*)&u0; qf1 = *(half4*)&u1;
    }

    floatx4 acc[4][2];
    #pragma unroll
    for (int cs = 0; cs < 4; ++cs)
        #pragma unroll
        for (int g = 0; g < 2; ++g) acc[cs][g] = (floatx4){0.f, 0.f, 0.f, 0.f};
    float dsum0 = 0.f, dsum1 = 0.f;

    uint2 k0_0,k0_1,k0_2,k0_3, k1_0,k1_1,k1_2,k1_3;
    uint2 h0_0,h0_1,h0_2,h0_3,h0_4,h0_5,h0_6,h0_7,h0_8,h0_9,h0_10,h0_11,h0_12,h0_13,h0_14,h0_15;
    uint2 h1_0,h1_1,h1_2,h1_3,h1_4,h1_5,h1_6,h1_7,h1_8,h1_9,h1_10,h1_11,h1_12,h1_13,h1_14,h1_15;

#define LDK(kt, SS) ((quad < 2) ? *(const uint2*)((kt) + ((SS)*16 + rm)*8 + 4*quad) : make_uint2(0,0))
#define LDH(ht, IDX) (*(const uint2*)((ht) + (IDX)*256 + lane*4))

#define LOADT(B, T) {                                                          \
    int tc = ((T) < NT) ? (T) : (NT-1);                                        \
    const u16* kt_ = kb + (size_t)tc*512;                                      \
    const u16* ht_ = hb + (size_t)tc*4096;                                     \
    k##B##_0 = LDK(kt_, 0); k##B##_1 = LDK(kt_, 1);                            \
    k##B##_2 = LDK(kt_, 2); k##B##_3 = LDK(kt_, 3);                            \
    h##B##_0  = LDH(ht_, 0);  h##B##_1  = LDH(ht_, 1);                         \
    h##B##_2  = LDH(ht_, 2);  h##B##_3  = LDH(ht_, 3);                         \
    h##B##_4  = LDH(ht_, 4);  h##B##_5  = LDH(ht_, 5);                         \
    h##B##_6  = LDH(ht_, 6);  h##B##_7  = LDH(ht_, 7);                         \
    h##B##_8  = LDH(ht_, 8);  h##B##_9  = LDH(ht_, 9);                         \
    h##B##_10 = LDH(ht_, 10); h##B##_11 = LDH(ht_, 11);                        \
    h##B##_12 = LDH(ht_, 12); h##B##_13 = LDH(ht_, 13);                        \
    h##B##_14 = LDH(ht_, 14); h##B##_15 = LDH(ht_, 15);                        \
}

#define COMPSS(KR, HA, HB_, HC, HD, T, SS) {                                   \
    half4 kf = *(half4*)&KR;                                                   \
    floatx4 s0 = {0.f,0.f,0.f,0.f}, s1 = {0.f,0.f,0.f,0.f};                    \
    s0 = __builtin_amdgcn_mfma_f32_16x16x16f16(kf, qf0, s0, 0, 0, 0);          \
    s1 = __builtin_amdgcn_mfma_f32_16x16x16f16(kf, qf1, s1, 0, 0, 0);          \
    half4 e0, e1;                                                              \
    int mb = (T)*64 + (SS)*16 + 4*quad;                                        \
    _Pragma("unroll")                                                          \
    for (int i_ = 0; i_ < 4; ++i_) {                                           \
        float ev0 = (mb + i_ < Ln) ? __expf(s0[i_]) : 0.f;                     \
        float ev1 = (mb + i_ < Ln) ? __expf(s1[i_]) : 0.f;                     \
        dsum0 += ev0; dsum1 += ev1;                                            \
        e0[i_] = (f16)ev0; e1[i_] = (f16)ev1;                                  \
    }                                                                          \
    half4 a0_ = *(half4*)&HA, a1_ = *(half4*)&HB_, a2_ = *(half4*)&HC, a3_ = *(half4*)&HD; \
    acc[0][0] = __builtin_amdgcn_mfma_f32_16x16x16f16(a0_, e0, acc[0][0], 0, 0, 0); \
    acc[0][1] = __builtin_amdgcn_mfma_f32_16x16x16f16(a0_, e1, acc[0][1], 0, 0, 0); \
    acc[1][0] = __builtin_amdgcn_mfma_f32_16x16x16f16(a1_, e0, acc[1][0], 0, 0, 0); \
    acc[1][1] = __builtin_amdgcn_mfma_f32_16x16x16f16(a1_, e1, acc[1][1], 0, 0, 0); \
    acc[2][0] = __builtin_amdgcn_mfma_f32_16x16x16f16(a2_, e0, acc[2][0], 0, 0, 0); \
    acc[2][1] = __builtin_amdgcn_mfma_f32_16x16x16f16(a2_, e1, acc[2][1], 0, 0, 0); \
    acc[3][0] = __builtin_amdgcn_mfma_f32_16x16x16f16(a3_, e0, acc[3][0], 0, 0, 0); \
    acc[3][1] = __builtin_amdgcn_mfma_f32_16x16x16f16(a3_, e1, acc[3][1], 0, 0, 0); \
}

#define COMPT(B, T) {                                                          \
    COMPSS(k##B##_0, h##B##_0,  h##B##_1,  h##B##_2,  h##B##_3,  T, 0)         \
    COMPSS(k##B##_1, h##B##_4,  h##B##_5,  h##B##_6,  h##B##_7,  T, 1)         \
    COMPSS(k##B##_2, h##B##_8,  h##B##_9,  h##B##_10, h##B##_11, T, 2)         \
    COMPSS(k##B##_3, h##B##_12, h##B##_13, h##B##_14, h##B##_15, T, 3)         \
}

    LOADT(0, w)
    for (int i = 0; i < 5; ++i) {
        int t0 = w + 8*i;
        LOADT(1, t0 + 4)
        COMPT(0, t0)
        LOADT(0, t0 + 8)
        COMPT(1, t0 + 4)
    }
#undef LOADT
#undef COMPT
#undef COMPSS
#undef LDK
#undef LDH

    {
        float s_ = dsum0;
        s_ += __shfl_xor(s_, 16, 64);
        s_ += __shfl_xor(s_, 32, 64);
        if (quad == 0) den_part[w][rm] = s_;
        float t_ = dsum1;
        t_ += __shfl_xor(t_, 16, 64);
        t_ += __shfl_xor(t_, 32, 64);
        if (quad == 0) den_part[w][16 + rm] = t_;
    }

    float* pw = part + w*1536;
    #pragma unroll
    for (int cs = 0; cs < 4; ++cs) {
        #pragma unroll
        for (int i = 0; i < 4; ++i)
            pw[(cs*16 + quad*4 + i)*24 + rm] = acc[cs][0][i];
        if (rm < 8) {
            #pragma unroll
            for (int i = 0; i < 4; ++i)
                pw[(cs*16 + quad*4 + i)*24 + 16 + rm] = acc[cs][1][i];
        }
    }
    __syncthreads();

    for (int j = tid; j < 1536; j += 256)
        part[j] = part[j] + part[1536 + j] + part[3072 + j] + part[4608 + j];
    __syncthreads();

    int o = tid & 63, rq = tid >> 6;
    float gam = gamma[0];
    float bvo = bv[o];
    const u16* wvr = wsu + U_WVT + o*64;
    uint4 wvu[8];
    #pragma unroll
    for (int x = 0; x < 8; ++x) wvu[x] = *(const uint4*)(wvr + x*8);
    #pragma unroll
    for (int rr = 0; rr < 6; ++rr) {
        int r = rq*6 + rr;
        int row = R0 + r;
        if (row < Ln) {
            float den = den_part[0][r] + den_part[1][r] + den_part[2][r] + den_part[3][r];
            float p = 0.f;
            #pragma unroll
            for (int x = 0; x < 8; ++x) {
                const f16* hh = (const f16*)&wvu[x];
                #pragma unroll
                for (int i = 0; i < 8; ++i)
                    p += (float)hh[i] * part[(x*8 + i)*24 + r];
            }
            size_t gi = ((size_t)b*Ln + row)*64 + o;
            out[gi] = gam*(bvo + p/den) + out[gi];
        }
    }
}

// ---------------- launch ----------------
extern "C" void kernel_launch(void* const* d_in, const int* in_sizes, int n_in,
                              void* d_out, int out_size, void* d_ws, size_t ws_size,
                              hipStream_t stream) {
    const float* X     = (const float*)d_in[0];
    const float* wA    = (const float*)d_in[1];
    const float* bA    = (const float*)d_in[2];
    const float* wB    = (const float*)d_in[3];
    const float* bB    = (const float*)d_in[4];
    const float* wq    = (const float*)d_in[5];
    const float* bq    = (const float*)d_in[6];
    const float* wk    = (const float*)d_in[7];
    const float* bk    = (const float*)d_in[8];
    const float* wv    = (const float*)d_in[9];
    const float* bv    = (const float*)d_in[10];
    const float* gamma = (const float*)d_in[11];
    float* out = (float*)d_out;
    float* ws  = (float*)d_ws;

    prep_kernel<<<98, 256, 0, stream>>>(wA, wB, wq, wk, wv, ws);
    conv_k_kernel<<<Bn*Nn, 256, 0, stream>>>(X, bA, bB, bk, bq, ws, out);
    attn_kernel<<<Bn*NB, 256, 0, stream>>>(gamma, bv, ws, out);
}